// Round 2
// baseline (400.849 us; speedup 1.0000x reference)
//
#include <hip/hip_runtime.h>
#include <hip/hip_bf16.h>

// ---------------------------------------------------------------------------
// CLIPAttentionPooling: q = x Wq^T + bq; k = x Wk^T + bk; S = q k^T;
// attn = softmax_rows(S); out = attn x.   N=4096, D=1024, fp32 in/out.
//
// Precision plan (R1 post-mortem: scores sigma=32, near-one-hot softmax
// amplifies S error; plain-bf16 path gave absmax 0.59 vs thr 0.0994):
//   - x, Wq, Wk, q, k carried as SPLIT bf16 (hi+lo planes, ~2^-17 rel).
//   - GEMMs on the x->S path use 3 MFMAs: Ah*Bh + Al*Bh + Ah*Bl.
//   - S materialized fp32; softmax fp32; attn cast bf16.
//   - out = attn * x in plain bf16 MFMA (error ~0.01 << threshold).
// ---------------------------------------------------------------------------

using short8  = __attribute__((ext_vector_type(8))) short;
using float4v = __attribute__((ext_vector_type(4))) float;

#define BM 128
#define BN 128
#define BK 32

#define GLOAD_LDS16(gptr, ldsptr)                                              \
  __builtin_amdgcn_global_load_lds(                                            \
      (__attribute__((address_space(1))) void*)(uintptr_t)(gptr),              \
      (__attribute__((address_space(3))) void*)(unsigned)(uintptr_t)(ldsptr),  \
      16, 0, 0)

// SPLIT=1: A,B given as hi/lo bf16 planes, 3-MFMA high-precision product.
// EP = 0: store fp32 (Ch).  EP = 1: add bias[col], split-store bf16 hi/lo.
template <int SPLIT, int EP>
__global__ __launch_bounds__(256) void gemm_bt(
    const __hip_bfloat16* __restrict__ Ah, const __hip_bfloat16* __restrict__ Al,
    const __hip_bfloat16* __restrict__ Bh, const __hip_bfloat16* __restrict__ Bl,
    const float* __restrict__ bias,
    void* __restrict__ Ch, void* __restrict__ Cl,
    int M, int N, int K)
{
  __shared__ __hip_bfloat16 sAh[BM * BK];
  __shared__ __hip_bfloat16 sBh[BN * BK];
  __shared__ __hip_bfloat16 sAl[SPLIT ? BM * BK : 64];
  __shared__ __hip_bfloat16 sBl[SPLIT ? BN * BK : 64];

  const int tid  = threadIdx.x;
  const int wave = tid >> 6;
  const int lane = tid & 63;
  const int quad = lane >> 4;
  const int t16  = lane & 15;
  const int wm   = wave & 1;   // wave row-half within 128x128 tile
  const int wn   = wave >> 1;  // wave col-half
  const int row0 = blockIdx.y * BM;
  const int col0 = blockIdx.x * BN;

  // staging: each lane moves 16B; 64B per 32-elem bf16 row -> 4 lanes/row
  const int seg  = lane & 3;   // 16B segment within a row
  const int rsub = lane >> 2;  // row within this wave's 16-row chunk

  float4v acc[4][4];
#pragma unroll
  for (int i = 0; i < 4; ++i)
#pragma unroll
    for (int j = 0; j < 4; ++j)
      acc[i][j] = (float4v){0.f, 0.f, 0.f, 0.f};

  for (int k0 = 0; k0 < K; k0 += BK) {
#pragma unroll
    for (int r = 0; r < 2; ++r) {
      const int trow = r * 64 + wave * 16;  // wave-uniform chunk base row
      const size_t goffA = (size_t)(row0 + trow + rsub) * K + k0 + seg * 8;
      const size_t goffB = (size_t)(col0 + trow + rsub) * K + k0 + seg * 8;
      GLOAD_LDS16(Ah + goffA, &sAh[trow * BK]);
      GLOAD_LDS16(Bh + goffB, &sBh[trow * BK]);
      if (SPLIT) {
        GLOAD_LDS16(Al + goffA, &sAl[trow * BK]);
        GLOAD_LDS16(Bl + goffB, &sBl[trow * BK]);
      }
    }
    __syncthreads();

    short8 afh[4], bfh[4];
    short8 afl[4], bfl[4];
#pragma unroll
    for (int i = 0; i < 4; ++i) {
      const int ar = (wm * 64 + i * 16 + t16) * BK + quad * 8;
      afh[i] = *(const short8*)&sAh[ar];
      if (SPLIT) afl[i] = *(const short8*)&sAl[ar];
    }
#pragma unroll
    for (int j = 0; j < 4; ++j) {
      const int br = (wn * 64 + j * 16 + t16) * BK + quad * 8;
      bfh[j] = *(const short8*)&sBh[br];
      if (SPLIT) bfl[j] = *(const short8*)&sBl[br];
    }

#pragma unroll
    for (int i = 0; i < 4; ++i)
#pragma unroll
      for (int j = 0; j < 4; ++j) {
        acc[i][j] = __builtin_amdgcn_mfma_f32_16x16x32_bf16(afh[i], bfh[j], acc[i][j], 0, 0, 0);
        if (SPLIT) {
          acc[i][j] = __builtin_amdgcn_mfma_f32_16x16x32_bf16(afl[i], bfh[j], acc[i][j], 0, 0, 0);
          acc[i][j] = __builtin_amdgcn_mfma_f32_16x16x32_bf16(afh[i], bfl[j], acc[i][j], 0, 0, 0);
        }
      }
    __syncthreads();
  }

  // epilogue: C/D layout col = lane&15, row = quad*4 + r  [verified m89]
#pragma unroll
  for (int i = 0; i < 4; ++i) {
#pragma unroll
    for (int j = 0; j < 4; ++j) {
      const int ccol = col0 + wn * 64 + j * 16 + t16;
#pragma unroll
      for (int r = 0; r < 4; ++r) {
        const int crow = row0 + wm * 64 + i * 16 + quad * 4 + r;
        float v = acc[i][j][r];
        if (EP == 0) {
          ((float*)Ch)[(size_t)crow * N + ccol] = v;
        } else {
          v += bias[ccol];
          __hip_bfloat16 h = __float2bfloat16(v);
          __hip_bfloat16 l = __float2bfloat16(v - __bfloat162float(h));
          ((__hip_bfloat16*)Ch)[(size_t)crow * N + ccol] = h;
          ((__hip_bfloat16*)Cl)[(size_t)crow * N + ccol] = l;
        }
      }
    }
  }
}

// fp32 -> split bf16 (hi = RN(v), lo = RN(v - hi)), 4 elems/thread
__global__ __launch_bounds__(256) void split_cast(
    const float* __restrict__ in,
    __hip_bfloat16* __restrict__ hi, __hip_bfloat16* __restrict__ lo, int n4)
{
  int i = blockIdx.x * blockDim.x + threadIdx.x;
  if (i < n4) {
    float4 v = ((const float4*)in)[i];
    union { __hip_bfloat16 h[4]; short4 s; } uh, ul;
    float vv[4] = {v.x, v.y, v.z, v.w};
#pragma unroll
    for (int c = 0; c < 4; ++c) {
      __hip_bfloat16 h = __float2bfloat16(vv[c]);
      uh.h[c] = h;
      ul.h[c] = __float2bfloat16(vv[c] - __bfloat162float(h));
    }
    ((short4*)hi)[i] = uh.s;
    ((short4*)lo)[i] = ul.s;
  }
}

// x [4096 x 1024] fp32 -> xT [1024 x 4096] bf16 (plain bf16: AV GEMM only)
__global__ __launch_bounds__(1024) void transpose_cast(
    const float* __restrict__ x, __hip_bfloat16* __restrict__ xT)
{
  __shared__ float tile[32][33];
  const int tx = threadIdx.x, ty = threadIdx.y;
  const int col = blockIdx.x * 32 + tx;   // D dim
  const int row = blockIdx.y * 32 + ty;   // N dim
  tile[ty][tx] = x[(size_t)row * 1024 + col];
  __syncthreads();
  xT[(size_t)(blockIdx.x * 32 + ty) * 4096 + blockIdx.y * 32 + tx] =
      __float2bfloat16(tile[tx][ty]);
}

// per-row softmax: S fp32 [4096 x 4096] -> attn bf16
__global__ __launch_bounds__(1024) void softmax_rows(
    const float* __restrict__ S, __hip_bfloat16* __restrict__ P)
{
  const int row = blockIdx.x;
  const size_t base = (size_t)row * 4096;
  const int tid = threadIdx.x;
  const int wid = tid >> 6, lane = tid & 63;
  __shared__ float red[16];

  float4 v = ((const float4*)(S + base))[tid];
  float m = fmaxf(fmaxf(v.x, v.y), fmaxf(v.z, v.w));
#pragma unroll
  for (int off = 32; off; off >>= 1) m = fmaxf(m, __shfl_xor(m, off));
  if (lane == 0) red[wid] = m;
  __syncthreads();
  float mall = red[0];
#pragma unroll
  for (int i = 1; i < 16; ++i) mall = fmaxf(mall, red[i]);

  float4 e;
  e.x = __expf(v.x - mall);
  e.y = __expf(v.y - mall);
  e.z = __expf(v.z - mall);
  e.w = __expf(v.w - mall);
  float s = e.x + e.y + e.z + e.w;
#pragma unroll
  for (int off = 32; off; off >>= 1) s += __shfl_xor(s, off);
  __syncthreads();
  if (lane == 0) red[wid] = s;
  __syncthreads();
  float sall = 0.f;
#pragma unroll
  for (int i = 0; i < 16; ++i) sall += red[i];
  const float inv = 1.0f / sall;

  union { __hip_bfloat16 h[4]; short4 s4; } u;
  u.h[0] = __float2bfloat16(e.x * inv);
  u.h[1] = __float2bfloat16(e.y * inv);
  u.h[2] = __float2bfloat16(e.z * inv);
  u.h[3] = __float2bfloat16(e.w * inv);
  ((short4*)(P + base))[tid] = u.s4;
}

extern "C" void kernel_launch(void* const* d_in, const int* in_sizes, int n_in,
                              void* d_out, int out_size, void* d_ws, size_t ws_size,
                              hipStream_t stream) {
  const int N = 4096, D = 1024;
  const float* x  = (const float*)d_in[0];
  const float* Wq = (const float*)d_in[1];
  const float* bq = (const float*)d_in[2];
  const float* Wk = (const float*)d_in[3];
  const float* bk = (const float*)d_in[4];
  float* out = (float*)d_out;

  // workspace layout (MiB offsets), total 128 MiB
  char* w = (char*)d_ws;
  const size_t MiB = 1024 * 1024;
  __hip_bfloat16* xh   = (__hip_bfloat16*)(w + 0  * MiB);  // [N x D] hi
  __hip_bfloat16* xl   = (__hip_bfloat16*)(w + 8  * MiB);  // [N x D] lo
  __hip_bfloat16* Wqh  = (__hip_bfloat16*)(w + 16 * MiB);  // [D x D]
  __hip_bfloat16* Wql  = (__hip_bfloat16*)(w + 18 * MiB);
  __hip_bfloat16* Wkh  = (__hip_bfloat16*)(w + 20 * MiB);
  __hip_bfloat16* Wkl  = (__hip_bfloat16*)(w + 22 * MiB);
  __hip_bfloat16* qh   = (__hip_bfloat16*)(w + 24 * MiB);  // [N x D]
  __hip_bfloat16* ql   = (__hip_bfloat16*)(w + 32 * MiB);
  __hip_bfloat16* kh   = (__hip_bfloat16*)(w + 40 * MiB);
  __hip_bfloat16* kl   = (__hip_bfloat16*)(w + 48 * MiB);
  __hip_bfloat16* xbT  = (__hip_bfloat16*)(w + 56 * MiB);  // [D x N]
  float*          S    = (float*)         (w + 64 * MiB);  // [N x N] fp32, 64 MiB
  __hip_bfloat16* attn = (__hip_bfloat16*)(w + 24 * MiB);  // [N x N] bf16, reuses q/k
                                                           // (q,k dead after S GEMM)

  // 1) split casts + transpose
  split_cast<<<(N * D / 4 + 255) / 256, 256, 0, stream>>>(x, xh, xl, N * D / 4);
  split_cast<<<(D * D / 4 + 255) / 256, 256, 0, stream>>>(Wq, Wqh, Wql, D * D / 4);
  split_cast<<<(D * D / 4 + 255) / 256, 256, 0, stream>>>(Wk, Wkh, Wkl, D * D / 4);
  transpose_cast<<<dim3(D / 32, N / 32), dim3(32, 32), 0, stream>>>(x, xbT);

  // 2) q,k projections (split in, split bf16 out, +bias)
  gemm_bt<1, 1><<<dim3(D / BN, N / BM), 256, 0, stream>>>(
      xh, xl, Wqh, Wql, bq, qh, ql, N, D, D);
  gemm_bt<1, 1><<<dim3(D / BN, N / BM), 256, 0, stream>>>(
      xh, xl, Wkh, Wkl, bk, kh, kl, N, D, D);

  // 3) S = q k^T (split in, fp32 out)
  gemm_bt<1, 0><<<dim3(N / BN, N / BM), 256, 0, stream>>>(
      qh, ql, kh, kl, nullptr, S, nullptr, N, N, D);

  // 4) softmax rows -> attn bf16
  softmax_rows<<<N, 1024, 0, stream>>>(S, attn);

  // 5) out = attn x  (plain bf16: A = attn [NxN], B = xbT [DxN], NT)
  gemm_bt<0, 0><<<dim3(D / BN, N / BM), 256, 0, stream>>>(
      attn, nullptr, xbT, nullptr, nullptr, out, nullptr, N, D, N);

  (void)in_sizes; (void)n_in; (void)out_size; (void)ws_size;
}

// Round 3
// 338.561 us; speedup vs baseline: 1.1840x; 1.1840x over previous
//
#include <hip/hip_runtime.h>
#include <hip/hip_bf16.h>
#include <hip/hip_fp16.h>
#include <stdint.h>

// ---------------------------------------------------------------------------
// CLIPAttentionPooling. R3: fused QK projection (N=2048, 512 blocks),
// split-K=2 AV GEMM (512 blocks), AV path in fp16 (calibration for a
// possible 2-MFMA fp16 S scheme). S path stays split-bf16 3-MFMA.
// ---------------------------------------------------------------------------

using short8  = __attribute__((ext_vector_type(8))) short;
using half8   = __attribute__((ext_vector_type(8))) _Float16;
using float4v = __attribute__((ext_vector_type(4))) float;

#define BM 128
#define BN 128
#define BK 32

#define GLOAD_LDS16(gptr, ldsptr)                                              \
  __builtin_amdgcn_global_load_lds(                                            \
      (__attribute__((address_space(1))) void*)(uintptr_t)(gptr),              \
      (__attribute__((address_space(3))) void*)(unsigned)(uintptr_t)(ldsptr),  \
      16, 0, 0)

// DT: 0 = bf16 MFMA, 1 = fp16 MFMA.
// SPLIT: hi/lo planes, 3-MFMA high-precision product.
// EP = 0: fp32 store to Ch (+ blockIdx.z * cz_stride).  EP = 1: add bias
// (biasQ for cols<1024 else biasK), split-store bf16 hi/lo to Ch/Cl.
template <int DT, int SPLIT, int EP>
__global__ __launch_bounds__(256) void gemm_bt(
    const uint16_t* __restrict__ Ah, const uint16_t* __restrict__ Al,
    const uint16_t* __restrict__ Bh, const uint16_t* __restrict__ Bl,
    const float* __restrict__ biasQ, const float* __restrict__ biasK,
    void* __restrict__ Ch, void* __restrict__ Cl,
    int lda, int ldb, int ldc, int k_span, size_t cz_stride)
{
  __shared__ uint16_t sAh[BM * BK];
  __shared__ uint16_t sBh[BN * BK];
  __shared__ uint16_t sAl[SPLIT ? BM * BK : 64];
  __shared__ uint16_t sBl[SPLIT ? BN * BK : 64];

  const int tid  = threadIdx.x;
  const int wave = tid >> 6;
  const int lane = tid & 63;
  const int quad = lane >> 4;
  const int t16  = lane & 15;
  const int wm   = wave & 1;
  const int wn   = wave >> 1;
  const int row0 = blockIdx.y * BM;
  const int col0 = blockIdx.x * BN;

  const int seg  = lane & 3;   // 16B segment within a 32-elem row
  const int rsub = lane >> 2;  // row within this wave's 16-row chunk

  const int k_begin = blockIdx.z * k_span;
  const int k_end   = k_begin + k_span;

  float4v acc[4][4];
#pragma unroll
  for (int i = 0; i < 4; ++i)
#pragma unroll
    for (int j = 0; j < 4; ++j)
      acc[i][j] = (float4v){0.f, 0.f, 0.f, 0.f};

  for (int k0 = k_begin; k0 < k_end; k0 += BK) {
#pragma unroll
    for (int r = 0; r < 2; ++r) {
      const int trow = r * 64 + wave * 16;  // wave-uniform chunk base row
      const size_t goffA = (size_t)(row0 + trow + rsub) * lda + k0 + seg * 8;
      const size_t goffB = (size_t)(col0 + trow + rsub) * ldb + k0 + seg * 8;
      GLOAD_LDS16(Ah + goffA, &sAh[trow * BK]);
      GLOAD_LDS16(Bh + goffB, &sBh[trow * BK]);
      if (SPLIT) {
        GLOAD_LDS16(Al + goffA, &sAl[trow * BK]);
        GLOAD_LDS16(Bl + goffB, &sBl[trow * BK]);
      }
    }
    __syncthreads();

    short8 afh[4], bfh[4];
    short8 afl[4], bfl[4];
#pragma unroll
    for (int i = 0; i < 4; ++i) {
      const int ar = (wm * 64 + i * 16 + t16) * BK + quad * 8;
      afh[i] = *(const short8*)&sAh[ar];
      if (SPLIT) afl[i] = *(const short8*)&sAl[ar];
    }
#pragma unroll
    for (int j = 0; j < 4; ++j) {
      const int br = (wn * 64 + j * 16 + t16) * BK + quad * 8;
      bfh[j] = *(const short8*)&sBh[br];
      if (SPLIT) bfl[j] = *(const short8*)&sBl[br];
    }

#pragma unroll
    for (int i = 0; i < 4; ++i)
#pragma unroll
      for (int j = 0; j < 4; ++j) {
        if (DT == 0) {
          acc[i][j] = __builtin_amdgcn_mfma_f32_16x16x32_bf16(afh[i], bfh[j], acc[i][j], 0, 0, 0);
          if (SPLIT) {
            acc[i][j] = __builtin_amdgcn_mfma_f32_16x16x32_bf16(afl[i], bfh[j], acc[i][j], 0, 0, 0);
            acc[i][j] = __builtin_amdgcn_mfma_f32_16x16x32_bf16(afh[i], bfl[j], acc[i][j], 0, 0, 0);
          }
        } else {
          acc[i][j] = __builtin_amdgcn_mfma_f32_16x16x32_f16(
              __builtin_bit_cast(half8, afh[i]), __builtin_bit_cast(half8, bfh[j]),
              acc[i][j], 0, 0, 0);
          if (SPLIT) {
            acc[i][j] = __builtin_amdgcn_mfma_f32_16x16x32_f16(
                __builtin_bit_cast(half8, afl[i]), __builtin_bit_cast(half8, bfh[j]),
                acc[i][j], 0, 0, 0);
            acc[i][j] = __builtin_amdgcn_mfma_f32_16x16x32_f16(
                __builtin_bit_cast(half8, afh[i]), __builtin_bit_cast(half8, bfl[j]),
                acc[i][j], 0, 0, 0);
          }
        }
      }
    __syncthreads();
  }

  // epilogue: C/D layout col = lane&15, row = quad*4 + r  [verified m89]
  const float* bp = nullptr;
  if (EP == 1) bp = (col0 < 1024) ? biasQ : (biasK - 1024);
#pragma unroll
  for (int i = 0; i < 4; ++i) {
#pragma unroll
    for (int j = 0; j < 4; ++j) {
      const int ccol = col0 + wn * 64 + j * 16 + t16;
#pragma unroll
      for (int r = 0; r < 4; ++r) {
        const int crow = row0 + wm * 64 + i * 16 + quad * 4 + r;
        float v = acc[i][j][r];
        if (EP == 0) {
          ((float*)Ch)[blockIdx.z * cz_stride + (size_t)crow * ldc + ccol] = v;
        } else {
          v += bp[ccol];
          __hip_bfloat16 h = __float2bfloat16(v);
          __hip_bfloat16 l = __float2bfloat16(v - __bfloat162float(h));
          ((uint16_t*)Ch)[(size_t)crow * ldc + ccol] = *(uint16_t*)&h;
          ((uint16_t*)Cl)[(size_t)crow * ldc + ccol] = *(uint16_t*)&l;
        }
      }
    }
  }
}

// fp32 -> split bf16 (hi = RN(v), lo = RN(v - hi)), 4 elems/thread
__global__ __launch_bounds__(256) void split_cast(
    const float* __restrict__ in,
    uint16_t* __restrict__ hi, uint16_t* __restrict__ lo, int n4)
{
  int i = blockIdx.x * blockDim.x + threadIdx.x;
  if (i < n4) {
    float4 v = ((const float4*)in)[i];
    union { __hip_bfloat16 h[4]; short4 s; } uh, ul;
    float vv[4] = {v.x, v.y, v.z, v.w};
#pragma unroll
    for (int c = 0; c < 4; ++c) {
      __hip_bfloat16 h = __float2bfloat16(vv[c]);
      uh.h[c] = h;
      ul.h[c] = __float2bfloat16(vv[c] - __bfloat162float(h));
    }
    ((short4*)hi)[i] = uh.s;
    ((short4*)lo)[i] = ul.s;
  }
}

// x [4096 x 1024] fp32 -> xT [1024 x 4096] fp16
__global__ __launch_bounds__(1024) void transpose_cast_f16(
    const float* __restrict__ x, uint16_t* __restrict__ xT)
{
  __shared__ float tile[32][33];
  const int tx = threadIdx.x, ty = threadIdx.y;
  const int col = blockIdx.x * 32 + tx;   // D dim
  const int row = blockIdx.y * 32 + ty;   // N dim
  tile[ty][tx] = x[(size_t)row * 1024 + col];
  __syncthreads();
  __half h = __float2half_rn(tile[tx][ty]);
  xT[(size_t)(blockIdx.x * 32 + ty) * 4096 + blockIdx.y * 32 + tx] = *(uint16_t*)&h;
}

// per-row softmax: S fp32 [4096 x 4096] -> attn fp16
__global__ __launch_bounds__(1024) void softmax_rows(
    const float* __restrict__ S, uint16_t* __restrict__ P)
{
  const int row = blockIdx.x;
  const size_t base = (size_t)row * 4096;
  const int tid = threadIdx.x;
  const int wid = tid >> 6, lane = tid & 63;
  __shared__ float red[16];

  float4 v = ((const float4*)(S + base))[tid];
  float m = fmaxf(fmaxf(v.x, v.y), fmaxf(v.z, v.w));
#pragma unroll
  for (int off = 32; off; off >>= 1) m = fmaxf(m, __shfl_xor(m, off));
  if (lane == 0) red[wid] = m;
  __syncthreads();
  float mall = red[0];
#pragma unroll
  for (int i = 1; i < 16; ++i) mall = fmaxf(mall, red[i]);

  float4 e;
  e.x = __expf(v.x - mall);
  e.y = __expf(v.y - mall);
  e.z = __expf(v.z - mall);
  e.w = __expf(v.w - mall);
  float s = e.x + e.y + e.z + e.w;
#pragma unroll
  for (int off = 32; off; off >>= 1) s += __shfl_xor(s, off);
  __syncthreads();
  if (lane == 0) red[wid] = s;
  __syncthreads();
  float sall = 0.f;
#pragma unroll
  for (int i = 0; i < 16; ++i) sall += red[i];
  const float inv = 1.0f / sall;

  union { __half h[4]; short4 s4; } u;
  u.h[0] = __float2half_rn(e.x * inv);
  u.h[1] = __float2half_rn(e.y * inv);
  u.h[2] = __float2half_rn(e.z * inv);
  u.h[3] = __float2half_rn(e.w * inv);
  ((short4*)P)[base / 4 + tid] = u.s4;
}

// out = p0 + p1 (split-K reduce), float4 per thread
__global__ __launch_bounds__(256) void add2(
    const float* __restrict__ p0, const float* __restrict__ p1,
    float* __restrict__ out, int n4)
{
  int i = blockIdx.x * blockDim.x + threadIdx.x;
  if (i < n4) {
    float4 a = ((const float4*)p0)[i];
    float4 b = ((const float4*)p1)[i];
    float4 o = {a.x + b.x, a.y + b.y, a.z + b.z, a.w + b.w};
    ((float4*)out)[i] = o;
  }
}

extern "C" void kernel_launch(void* const* d_in, const int* in_sizes, int n_in,
                              void* d_out, int out_size, void* d_ws, size_t ws_size,
                              hipStream_t stream) {
  const int N = 4096, D = 1024;
  const float* x  = (const float*)d_in[0];
  const float* Wq = (const float*)d_in[1];
  const float* bq = (const float*)d_in[2];
  const float* Wk = (const float*)d_in[3];
  const float* bk = (const float*)d_in[4];
  float* out = (float*)d_out;

  // workspace layout (MiB offsets), total 128 MiB
  char* w = (char*)d_ws;
  const size_t MiB = 1024 * 1024;
  uint16_t* xh    = (uint16_t*)(w + 0  * MiB);  // [N x D] bf16 hi
  uint16_t* xl    = (uint16_t*)(w + 8  * MiB);  // [N x D] bf16 lo
  uint16_t* Wqkh  = (uint16_t*)(w + 16 * MiB);  // [2048 x 1024] bf16 (Wq; Wk)
  uint16_t* Wqkl  = (uint16_t*)(w + 20 * MiB);
  uint16_t* qkh   = (uint16_t*)(w + 24 * MiB);  // [N x 2048] bf16 (q | k)
  uint16_t* qkl   = (uint16_t*)(w + 40 * MiB);
  uint16_t* xTh   = (uint16_t*)(w + 56 * MiB);  // [D x N] fp16
  float*    S     = (float*)   (w + 64 * MiB);  // [N x N] fp32, 64 MiB
  uint16_t* attn  = (uint16_t*)(w + 24 * MiB);  // [N x N] fp16 (reuses qk, dead after S)
  float*    part  = (float*)   (w + 64 * MiB);  // 2 x [N x D] fp32 (reuses S)

  // 1) casts: x split, Wq/Wk split stacked into Wqk, x^T fp16
  split_cast<<<N * D / 4 / 256, 256, 0, stream>>>(x, xh, xl, N * D / 4);
  split_cast<<<D * D / 4 / 256, 256, 0, stream>>>(Wq, Wqkh, Wqkl, D * D / 4);
  split_cast<<<D * D / 4 / 256, 256, 0, stream>>>(Wk, Wqkh + (size_t)D * D,
                                                  Wqkl + (size_t)D * D, D * D / 4);
  transpose_cast_f16<<<dim3(D / 32, N / 32), dim3(32, 32), 0, stream>>>(x, xTh);

  // 2) fused qk projection: [N x 2048] = x [N x 1024] * Wqk^T, split bf16 out
  gemm_bt<0, 1, 1><<<dim3(2048 / BN, N / BM), 256, 0, stream>>>(
      xh, xl, Wqkh, Wqkl, bq, bk, qkh, qkl,
      /*lda=*/D, /*ldb=*/D, /*ldc=*/2048, /*k_span=*/D, 0);

  // 3) S = q k^T (split bf16, fp32 out). A = qk cols 0..1023, B = cols 1024..2047
  gemm_bt<0, 1, 0><<<dim3(N / BN, N / BM), 256, 0, stream>>>(
      qkh, qkl, qkh + 1024, qkl + 1024, nullptr, nullptr, S, nullptr,
      /*lda=*/2048, /*ldb=*/2048, /*ldc=*/N, /*k_span=*/D, 0);

  // 4) softmax rows -> attn fp16
  softmax_rows<<<N, 1024, 0, stream>>>(S, attn);

  // 5) out = attn * x, fp16, split-K=2 into partials (over dead S memory)
  gemm_bt<1, 0, 0><<<dim3(D / BN, N / BM, 2), 256, 0, stream>>>(
      attn, nullptr, xTh, nullptr, nullptr, nullptr, part, nullptr,
      /*lda=*/N, /*ldb=*/N, /*ldc=*/D, /*k_span=*/N / 2, (size_t)N * D);

  // 6) reduce partials
  add2<<<N * D / 4 / 256, 256, 0, stream>>>(part, part + (size_t)N * D, out, N * D / 4);

  (void)in_sizes; (void)n_in; (void)out_size; (void)ws_size;
}

// Round 4
// 292.258 us; speedup vs baseline: 1.3716x; 1.1584x over previous
//
#include <hip/hip_runtime.h>
#include <hip/hip_bf16.h>
#include <hip/hip_fp16.h>
#include <stdint.h>

// ---------------------------------------------------------------------------
// CLIPAttentionPooling. R4: S = q k^T via int8 fixed-point split GEMM
// (q ~ s*(256*hi+lo), 3 i8 MFMAs at 2x bf16 rate, exact i32 accumulation,
// lo*lo dropped). Proj epilogue quantizes q,k to i8 planes. attn (fp16)
// written in-place into S rows. Proj stays split-bf16 3-MFMA.
// ---------------------------------------------------------------------------

using short8  = __attribute__((ext_vector_type(8))) short;
using half8   = __attribute__((ext_vector_type(8))) _Float16;
using float4v = __attribute__((ext_vector_type(4))) float;
using int4v   = __attribute__((ext_vector_type(4))) int;

#define BM 128
#define BN 128
#define BK 32

// i8 quantization: covers +-6.0 in int16, split into two i8 planes.
#define QS        (6.0f / 32768.0f)           // lsb of the int16 grid
#define INV_S     (32768.0f / 6.0f)
#define INV_S256  (128.0f / 6.0f)             // 1/(256*QS)
#define C_HH      (65536.0f * QS * QS)        // weight of hh accumulator
#define C_X       (256.0f * QS * QS)          // weight of cross accumulator

#define GLOAD_LDS16(gptr, ldsptr)                                              \
  __builtin_amdgcn_global_load_lds(                                            \
      (__attribute__((address_space(1))) void*)(uintptr_t)(gptr),              \
      (__attribute__((address_space(3))) void*)(unsigned)(uintptr_t)(ldsptr),  \
      16, 0, 0)

// DT: 0 = bf16 MFMA, 1 = fp16 MFMA.
// SPLIT: hi/lo planes, 3-MFMA high-precision product.
// EP = 0: fp32 store to Ch (+ blockIdx.z * cz_stride).
// EP = 1: add bias (biasQ for cols<1024 else biasK), quantize to i8 hi/lo
//         planes stored to Ch/Cl (row stride ldc, int8).
template <int DT, int SPLIT, int EP>
__global__ __launch_bounds__(256) void gemm_bt(
    const uint16_t* __restrict__ Ah, const uint16_t* __restrict__ Al,
    const uint16_t* __restrict__ Bh, const uint16_t* __restrict__ Bl,
    const float* __restrict__ biasQ, const float* __restrict__ biasK,
    void* __restrict__ Ch, void* __restrict__ Cl,
    int lda, int ldb, int ldc, int k_span, size_t cz_stride)
{
  __shared__ uint16_t sAh[BM * BK];
  __shared__ uint16_t sBh[BN * BK];
  __shared__ uint16_t sAl[SPLIT ? BM * BK : 64];
  __shared__ uint16_t sBl[SPLIT ? BN * BK : 64];

  const int tid  = threadIdx.x;
  const int wave = tid >> 6;
  const int lane = tid & 63;
  const int quad = lane >> 4;
  const int t16  = lane & 15;
  const int wm   = wave & 1;
  const int wn   = wave >> 1;
  const int row0 = blockIdx.y * BM;
  const int col0 = blockIdx.x * BN;

  const int seg  = lane & 3;   // 16B segment within a 32-elem row
  const int rsub = lane >> 2;  // row within this wave's 16-row chunk

  const int k_begin = blockIdx.z * k_span;
  const int k_end   = k_begin + k_span;

  float4v acc[4][4];
#pragma unroll
  for (int i = 0; i < 4; ++i)
#pragma unroll
    for (int j = 0; j < 4; ++j)
      acc[i][j] = (float4v){0.f, 0.f, 0.f, 0.f};

  for (int k0 = k_begin; k0 < k_end; k0 += BK) {
#pragma unroll
    for (int r = 0; r < 2; ++r) {
      const int trow = r * 64 + wave * 16;  // wave-uniform chunk base row
      const size_t goffA = (size_t)(row0 + trow + rsub) * lda + k0 + seg * 8;
      const size_t goffB = (size_t)(col0 + trow + rsub) * ldb + k0 + seg * 8;
      GLOAD_LDS16(Ah + goffA, &sAh[trow * BK]);
      GLOAD_LDS16(Bh + goffB, &sBh[trow * BK]);
      if (SPLIT) {
        GLOAD_LDS16(Al + goffA, &sAl[trow * BK]);
        GLOAD_LDS16(Bl + goffB, &sBl[trow * BK]);
      }
    }
    __syncthreads();

    short8 afh[4], bfh[4];
    short8 afl[4], bfl[4];
#pragma unroll
    for (int i = 0; i < 4; ++i) {
      const int ar = (wm * 64 + i * 16 + t16) * BK + quad * 8;
      afh[i] = *(const short8*)&sAh[ar];
      if (SPLIT) afl[i] = *(const short8*)&sAl[ar];
    }
#pragma unroll
    for (int j = 0; j < 4; ++j) {
      const int br = (wn * 64 + j * 16 + t16) * BK + quad * 8;
      bfh[j] = *(const short8*)&sBh[br];
      if (SPLIT) bfl[j] = *(const short8*)&sBl[br];
    }

#pragma unroll
    for (int i = 0; i < 4; ++i)
#pragma unroll
      for (int j = 0; j < 4; ++j) {
        if (DT == 0) {
          acc[i][j] = __builtin_amdgcn_mfma_f32_16x16x32_bf16(afh[i], bfh[j], acc[i][j], 0, 0, 0);
          if (SPLIT) {
            acc[i][j] = __builtin_amdgcn_mfma_f32_16x16x32_bf16(afl[i], bfh[j], acc[i][j], 0, 0, 0);
            acc[i][j] = __builtin_amdgcn_mfma_f32_16x16x32_bf16(afh[i], bfl[j], acc[i][j], 0, 0, 0);
          }
        } else {
          acc[i][j] = __builtin_amdgcn_mfma_f32_16x16x32_f16(
              __builtin_bit_cast(half8, afh[i]), __builtin_bit_cast(half8, bfh[j]),
              acc[i][j], 0, 0, 0);
          if (SPLIT) {
            acc[i][j] = __builtin_amdgcn_mfma_f32_16x16x32_f16(
                __builtin_bit_cast(half8, afl[i]), __builtin_bit_cast(half8, bfh[j]),
                acc[i][j], 0, 0, 0);
            acc[i][j] = __builtin_amdgcn_mfma_f32_16x16x32_f16(
                __builtin_bit_cast(half8, afh[i]), __builtin_bit_cast(half8, bfl[j]),
                acc[i][j], 0, 0, 0);
          }
        }
      }
    __syncthreads();
  }

  // epilogue: C/D layout col = lane&15, row = quad*4 + r  [verified m89]
  const float* bp = nullptr;
  if (EP == 1) bp = (col0 < 1024) ? biasQ : (biasK - 1024);
#pragma unroll
  for (int i = 0; i < 4; ++i) {
#pragma unroll
    for (int j = 0; j < 4; ++j) {
      const int ccol = col0 + wn * 64 + j * 16 + t16;
#pragma unroll
      for (int r = 0; r < 4; ++r) {
        const int crow = row0 + wm * 64 + i * 16 + quad * 4 + r;
        float v = acc[i][j][r];
        if (EP == 0) {
          ((float*)Ch)[blockIdx.z * cz_stride + (size_t)crow * ldc + ccol] = v;
        } else {
          v += bp[ccol];
          // quantize to int16 grid, split into i8 hi/lo planes
          int hi = (int)lrintf(v * INV_S256);
          hi = hi > 127 ? 127 : (hi < -127 ? -127 : hi);
          int lo = (int)lrintf(v * INV_S - 256.0f * (float)hi);
          lo = lo > 127 ? 127 : (lo < -127 ? -127 : lo);
          ((int8_t*)Ch)[(size_t)crow * ldc + ccol] = (int8_t)hi;
          ((int8_t*)Cl)[(size_t)crow * ldc + ccol] = (int8_t)lo;
        }
      }
    }
  }
}

// S = q k^T via i8 split planes. M=N=4096, K=1024, lda=ldb=2048, ldc=4096.
// S_f32 = C_HH * hh + C_X * (hi*lo + lo*hi)   (lo*lo dropped, ~6e-3 rms)
__global__ __launch_bounds__(256, 2) void gemm_s_i8(
    const int8_t* __restrict__ Ahi, const int8_t* __restrict__ Alo,
    const int8_t* __restrict__ Bhi, const int8_t* __restrict__ Blo,
    float* __restrict__ S)
{
  __shared__ __align__(16) int8_t sAh[128 * 64];
  __shared__ __align__(16) int8_t sAl[128 * 64];
  __shared__ __align__(16) int8_t sBh[128 * 64];
  __shared__ __align__(16) int8_t sBl[128 * 64];

  const int tid  = threadIdx.x;
  const int wave = tid >> 6;
  const int lane = tid & 63;
  const int quad = lane >> 4;
  const int t16  = lane & 15;
  const int wm   = wave & 1;
  const int wn   = wave >> 1;
  const int row0 = blockIdx.y * 128;
  const int col0 = blockIdx.x * 128;

  const int seg  = lane & 3;   // 16B segment within a 64-byte row
  const int rsub = lane >> 2;  // row within this wave's 16-row chunk

  int4v hh[4][4], cc[4][4];
#pragma unroll
  for (int i = 0; i < 4; ++i)
#pragma unroll
    for (int j = 0; j < 4; ++j) {
      hh[i][j] = (int4v){0, 0, 0, 0};
      cc[i][j] = (int4v){0, 0, 0, 0};
    }

  for (int k0 = 0; k0 < 1024; k0 += 64) {
#pragma unroll
    for (int r = 0; r < 2; ++r) {
      const int trow = r * 64 + wave * 16;
      const size_t goffA = (size_t)(row0 + trow + rsub) * 2048 + k0 + seg * 16;
      const size_t goffB = (size_t)(col0 + trow + rsub) * 2048 + k0 + seg * 16;
      GLOAD_LDS16(Ahi + goffA, &sAh[trow * 64]);
      GLOAD_LDS16(Alo + goffA, &sAl[trow * 64]);
      GLOAD_LDS16(Bhi + goffB, &sBh[trow * 64]);
      GLOAD_LDS16(Blo + goffB, &sBl[trow * 64]);
    }
    __syncthreads();

    // A-frag layout (by analogy w/ verified bf16 K-doubling): lane holds
    // A[m = lane&15][k = quad*16 + 0..15] -> one b128 per subtile per plane.
    int4v ah[4], al[4], bh[4], bl[4];
#pragma unroll
    for (int i = 0; i < 4; ++i) {
      const int ar = (wm * 64 + i * 16 + t16) * 64 + quad * 16;
      ah[i] = *(const int4v*)&sAh[ar];
      al[i] = *(const int4v*)&sAl[ar];
    }
#pragma unroll
    for (int j = 0; j < 4; ++j) {
      const int br = (wn * 64 + j * 16 + t16) * 64 + quad * 16;
      bh[j] = *(const int4v*)&sBh[br];
      bl[j] = *(const int4v*)&sBl[br];
    }

#pragma unroll
    for (int i = 0; i < 4; ++i)
#pragma unroll
      for (int j = 0; j < 4; ++j) {
        hh[i][j] = __builtin_amdgcn_mfma_i32_16x16x64_i8(ah[i], bh[j], hh[i][j], 0, 0, 0);
        cc[i][j] = __builtin_amdgcn_mfma_i32_16x16x64_i8(ah[i], bl[j], cc[i][j], 0, 0, 0);
        cc[i][j] = __builtin_amdgcn_mfma_i32_16x16x64_i8(al[i], bh[j], cc[i][j], 0, 0, 0);
      }
    __syncthreads();
  }

#pragma unroll
  for (int i = 0; i < 4; ++i) {
#pragma unroll
    for (int j = 0; j < 4; ++j) {
      const int ccol = col0 + wn * 64 + j * 16 + t16;
#pragma unroll
      for (int r = 0; r < 4; ++r) {
        const int crow = row0 + wm * 64 + i * 16 + quad * 4 + r;
        S[(size_t)crow * 4096 + ccol] =
            C_HH * (float)hh[i][j][r] + C_X * (float)cc[i][j][r];
      }
    }
  }
}

// fp32 -> split bf16 (hi = RN(v), lo = RN(v - hi)), 4 elems/thread
__global__ __launch_bounds__(256) void split_cast(
    const float* __restrict__ in,
    uint16_t* __restrict__ hi, uint16_t* __restrict__ lo, int n4)
{
  int i = blockIdx.x * blockDim.x + threadIdx.x;
  if (i < n4) {
    float4 v = ((const float4*)in)[i];
    union { __hip_bfloat16 h[4]; short4 s; } uh, ul;
    float vv[4] = {v.x, v.y, v.z, v.w};
#pragma unroll
    for (int c = 0; c < 4; ++c) {
      __hip_bfloat16 h = __float2bfloat16(vv[c]);
      uh.h[c] = h;
      ul.h[c] = __float2bfloat16(vv[c] - __bfloat162float(h));
    }
    ((short4*)hi)[i] = uh.s;
    ((short4*)lo)[i] = ul.s;
  }
}

// x [4096 x 1024] fp32 -> xT [1024 x 4096] fp16
__global__ __launch_bounds__(1024) void transpose_cast_f16(
    const float* __restrict__ x, uint16_t* __restrict__ xT)
{
  __shared__ float tile[32][33];
  const int tx = threadIdx.x, ty = threadIdx.y;
  const int col = blockIdx.x * 32 + tx;   // D dim
  const int row = blockIdx.y * 32 + ty;   // N dim
  tile[ty][tx] = x[(size_t)row * 1024 + col];
  __syncthreads();
  __half h = __float2half_rn(tile[tx][ty]);
  xT[(size_t)(blockIdx.x * 32 + ty) * 4096 + blockIdx.y * 32 + tx] = *(uint16_t*)&h;
}

// per-row softmax over S fp32 [4096 x 4096]; attn fp16 written IN-PLACE into
// the first half of each S row (row stride stays 16KB = 8192 uint16 elems).
// Row-local: all reads of the row happen before the first __syncthreads.
__global__ __launch_bounds__(1024) void softmax_rows(
    float* __restrict__ S)
{
  const int row = blockIdx.x;
  const size_t base = (size_t)row * 4096;
  const int tid = threadIdx.x;
  const int wid = tid >> 6, lane = tid & 63;
  __shared__ float red[16];

  float4 v = ((const float4*)(S + base))[tid];
  float m = fmaxf(fmaxf(v.x, v.y), fmaxf(v.z, v.w));
#pragma unroll
  for (int off = 32; off; off >>= 1) m = fmaxf(m, __shfl_xor(m, off));
  if (lane == 0) red[wid] = m;
  __syncthreads();
  float mall = red[0];
#pragma unroll
  for (int i = 1; i < 16; ++i) mall = fmaxf(mall, red[i]);

  float4 e;
  e.x = __expf(v.x - mall);
  e.y = __expf(v.y - mall);
  e.z = __expf(v.z - mall);
  e.w = __expf(v.w - mall);
  float s = e.x + e.y + e.z + e.w;
#pragma unroll
  for (int off = 32; off; off >>= 1) s += __shfl_xor(s, off);
  __syncthreads();
  if (lane == 0) red[wid] = s;
  __syncthreads();
  float sall = 0.f;
#pragma unroll
  for (int i = 0; i < 16; ++i) sall += red[i];
  const float inv = 1.0f / sall;

  union { __half h[4]; short4 s4; } u;
  u.h[0] = __float2half_rn(e.x * inv);
  u.h[1] = __float2half_rn(e.y * inv);
  u.h[2] = __float2half_rn(e.z * inv);
  u.h[3] = __float2half_rn(e.w * inv);
  // uint16 row stride = 8192; short4 index = (row*8192 + 4*tid)/4
  ((short4*)S)[(size_t)row * 2048 + tid] = u.s4;
}

// out = p0 + p1 (split-K reduce), float4 per thread
__global__ __launch_bounds__(256) void add2(
    const float* __restrict__ p0, const float* __restrict__ p1,
    float* __restrict__ out, int n4)
{
  int i = blockIdx.x * blockDim.x + threadIdx.x;
  if (i < n4) {
    float4 a = ((const float4*)p0)[i];
    float4 b = ((const float4*)p1)[i];
    float4 o = {a.x + b.x, a.y + b.y, a.z + b.z, a.w + b.w};
    ((float4*)out)[i] = o;
  }
}

extern "C" void kernel_launch(void* const* d_in, const int* in_sizes, int n_in,
                              void* d_out, int out_size, void* d_ws, size_t ws_size,
                              hipStream_t stream) {
  const int N = 4096, D = 1024;
  const float* x  = (const float*)d_in[0];
  const float* Wq = (const float*)d_in[1];
  const float* bq = (const float*)d_in[2];
  const float* Wk = (const float*)d_in[3];
  const float* bk = (const float*)d_in[4];
  float* out = (float*)d_out;

  // workspace layout (MiB offsets), total 112 MiB
  char* w = (char*)d_ws;
  const size_t MiB = 1024 * 1024;
  uint16_t* xh    = (uint16_t*)(w + 0  * MiB);  // [N x D] bf16 hi   (dead after proj)
  uint16_t* xl    = (uint16_t*)(w + 8  * MiB);  // [N x D] bf16 lo   (dead after proj)
  uint16_t* Wqkh  = (uint16_t*)(w + 16 * MiB);  // [2048 x 1024] bf16 (dead after proj)
  uint16_t* Wqkl  = (uint16_t*)(w + 20 * MiB);
  uint16_t* xTh   = (uint16_t*)(w + 24 * MiB);  // [D x N] fp16      (live until AV)
  int8_t*   qk_hi = (int8_t*)  (w + 32 * MiB);  // [N x 2048] i8 hi  (dead after S)
  int8_t*   qk_lo = (int8_t*)  (w + 40 * MiB);  // [N x 2048] i8 lo  (dead after S)
  float*    S     = (float*)   (w + 48 * MiB);  // [N x N] fp32, 64 MiB
  float*    part0 = (float*)   (w + 0  * MiB);  // [N x D] fp32 (reuses xh/xl)
  float*    part1 = (float*)   (w + 32 * MiB);  // [N x D] fp32 (reuses qk)

  // 1) casts: x split, Wq/Wk split stacked into Wqk, x^T fp16
  split_cast<<<N * D / 4 / 256, 256, 0, stream>>>(x, xh, xl, N * D / 4);
  split_cast<<<D * D / 4 / 256, 256, 0, stream>>>(Wq, Wqkh, Wqkl, D * D / 4);
  split_cast<<<D * D / 4 / 256, 256, 0, stream>>>(Wk, Wqkh + (size_t)D * D,
                                                  Wqkl + (size_t)D * D, D * D / 4);
  transpose_cast_f16<<<dim3(D / 32, N / 32), dim3(32, 32), 0, stream>>>(x, xTh);

  // 2) fused qk projection (split bf16 3-MFMA) -> i8 hi/lo planes [N x 2048]
  gemm_bt<0, 1, 1><<<dim3(2048 / BN, N / BM), 256, 0, stream>>>(
      xh, xl, Wqkh, Wqkl, bq, bk, qk_hi, qk_lo,
      /*lda=*/D, /*ldb=*/D, /*ldc=*/2048, /*k_span=*/D, 0);

  // 3) S = q k^T via i8 split GEMM (q = cols 0..1023, k = cols 1024..2047)
  gemm_s_i8<<<dim3(N / BN, N / BM), 256, 0, stream>>>(
      qk_hi, qk_lo, qk_hi + 1024, qk_lo + 1024, S);

  // 4) softmax rows, attn fp16 in-place into S rows (stride 8192 uint16)
  softmax_rows<<<N, 1024, 0, stream>>>(S);

  // 5) out = attn * x, fp16, split-K=2 into partials
  gemm_bt<1, 0, 0><<<dim3(D / BN, N / BM, 2), 256, 0, stream>>>(
      (const uint16_t*)S, nullptr, xTh, nullptr, nullptr, nullptr, part0, nullptr,
      /*lda=*/8192, /*ldb=*/N, /*ldc=*/D, /*k_span=*/N / 2, (size_t)32 * MiB / 4);

  // 6) reduce partials (part1 = part0 + 32 MiB via cz_stride above)
  add2<<<N * D / 4 / 256, 256, 0, stream>>>(part0, part1, out, N * D / 4);

  (void)in_sizes; (void)n_in; (void)out_size; (void)ws_size;
}

// Round 5
// 268.559 us; speedup vs baseline: 1.4926x; 1.0882x over previous
//
#include <hip/hip_runtime.h>
#include <hip/hip_bf16.h>
#include <hip/hip_fp16.h>
#include <stdint.h>

// ---------------------------------------------------------------------------
// CLIPAttentionPooling. R5: (1) AV GEMM gets XCD-aware block swizzle so the
// 8 column-blocks sharing an attn row-band co-locate on one XCD's L2
// (R4: 170 MB FETCH = 8x attn re-fetch across XCDs, 57 us memory floor).
// (2) QK projection moves to i8 split planes, 4 MFMAs (exact int16 product)
// at 2x bf16 rate. (3) S stays i8 split 3-MFMA; softmax in-place; AV fp16.
// ---------------------------------------------------------------------------

using short8  = __attribute__((ext_vector_type(8))) short;
using half8   = __attribute__((ext_vector_type(8))) _Float16;
using float4v = __attribute__((ext_vector_type(4))) float;
using int4v   = __attribute__((ext_vector_type(4))) int;

// q/k int16 grid: covers +-6.0, split into two i8 planes (v = QS*(256*hi+lo))
#define QS        (6.0f / 32768.0f)
#define INV_S     (32768.0f / 6.0f)
#define INV_S256  (128.0f / 6.0f)
#define C_HH      (65536.0f * QS * QS)
#define C_X       (256.0f * QS * QS)

// x grid: +-6.0 ; W grid: +-0.25
#define SX        (6.0f / 32768.0f)
#define SW        (0.25f / 32768.0f)
#define P_HH      (65536.0f * SX * SW)
#define P_X       (256.0f * SX * SW)
#define P_LL      (SX * SW)

#define GLOAD_LDS16(gptr, ldsptr)                                              \
  __builtin_amdgcn_global_load_lds(                                            \
      (__attribute__((address_space(1))) void*)(uintptr_t)(gptr),              \
      (__attribute__((address_space(3))) void*)(unsigned)(uintptr_t)(ldsptr),  \
      16, 0, 0)

// ---------------------------------------------------------------------------
// S = q k^T via i8 split planes (3 MFMAs, lo*lo dropped ~6e-3 rms).
// M=N=4096, K=1024, lda=ldb=2048, ldc=4096. 128x128 tile.
__global__ __launch_bounds__(256, 2) void gemm_s_i8(
    const int8_t* __restrict__ Ahi, const int8_t* __restrict__ Alo,
    const int8_t* __restrict__ Bhi, const int8_t* __restrict__ Blo,
    float* __restrict__ S)
{
  __shared__ __align__(16) int8_t sAh[128 * 64];
  __shared__ __align__(16) int8_t sAl[128 * 64];
  __shared__ __align__(16) int8_t sBh[128 * 64];
  __shared__ __align__(16) int8_t sBl[128 * 64];

  const int tid  = threadIdx.x;
  const int wave = tid >> 6;
  const int lane = tid & 63;
  const int quad = lane >> 4;
  const int t16  = lane & 15;
  const int wm   = wave & 1;
  const int wn   = wave >> 1;
  const int row0 = blockIdx.y * 128;
  const int col0 = blockIdx.x * 128;

  const int seg  = lane & 3;
  const int rsub = lane >> 2;

  int4v hh[4][4], cc[4][4];
#pragma unroll
  for (int i = 0; i < 4; ++i)
#pragma unroll
    for (int j = 0; j < 4; ++j) {
      hh[i][j] = (int4v){0, 0, 0, 0};
      cc[i][j] = (int4v){0, 0, 0, 0};
    }

  for (int k0 = 0; k0 < 1024; k0 += 64) {
#pragma unroll
    for (int r = 0; r < 2; ++r) {
      const int trow = r * 64 + wave * 16;
      const size_t goffA = (size_t)(row0 + trow + rsub) * 2048 + k0 + seg * 16;
      const size_t goffB = (size_t)(col0 + trow + rsub) * 2048 + k0 + seg * 16;
      GLOAD_LDS16(Ahi + goffA, &sAh[trow * 64]);
      GLOAD_LDS16(Alo + goffA, &sAl[trow * 64]);
      GLOAD_LDS16(Bhi + goffB, &sBh[trow * 64]);
      GLOAD_LDS16(Blo + goffB, &sBl[trow * 64]);
    }
    __syncthreads();

    // i8 16x16x64 A-frag: lane holds A[m=lane&15][k=quad*16+0..15] (verified R4)
    int4v ah[4], al[4], bh[4], bl[4];
#pragma unroll
    for (int i = 0; i < 4; ++i) {
      const int ar = (wm * 64 + i * 16 + t16) * 64 + quad * 16;
      ah[i] = *(const int4v*)&sAh[ar];
      al[i] = *(const int4v*)&sAl[ar];
    }
#pragma unroll
    for (int j = 0; j < 4; ++j) {
      const int br = (wn * 64 + j * 16 + t16) * 64 + quad * 16;
      bh[j] = *(const int4v*)&sBh[br];
      bl[j] = *(const int4v*)&sBl[br];
    }

#pragma unroll
    for (int i = 0; i < 4; ++i)
#pragma unroll
      for (int j = 0; j < 4; ++j) {
        hh[i][j] = __builtin_amdgcn_mfma_i32_16x16x64_i8(ah[i], bh[j], hh[i][j], 0, 0, 0);
        cc[i][j] = __builtin_amdgcn_mfma_i32_16x16x64_i8(ah[i], bl[j], cc[i][j], 0, 0, 0);
        cc[i][j] = __builtin_amdgcn_mfma_i32_16x16x64_i8(al[i], bh[j], cc[i][j], 0, 0, 0);
      }
    __syncthreads();
  }

#pragma unroll
  for (int i = 0; i < 4; ++i) {
#pragma unroll
    for (int j = 0; j < 4; ++j) {
      const int ccol = col0 + wn * 64 + j * 16 + t16;
#pragma unroll
      for (int r = 0; r < 4; ++r) {
        const int crow = row0 + wm * 64 + i * 16 + quad * 4 + r;
        S[(size_t)crow * 4096 + ccol] =
            C_HH * (float)hh[i][j][r] + C_X * (float)cc[i][j][r];
      }
    }
  }
}

// ---------------------------------------------------------------------------
// qk = x Wqk^T + bias via i8 split planes, 4 MFMAs (EXACT int16 product).
// M=4096, N=2048, K=1024. BM=128, BN=64 (3 acc sets need the registers).
// Epilogue quantizes to q/k i8 hi/lo planes (QS grid), ldc=2048.
__global__ __launch_bounds__(256) void gemm_proj_i8(
    const int8_t* __restrict__ Ahi, const int8_t* __restrict__ Alo,
    const int8_t* __restrict__ Bhi, const int8_t* __restrict__ Blo,
    const float* __restrict__ biasQ, const float* __restrict__ biasK,
    int8_t* __restrict__ Ch, int8_t* __restrict__ Cl)
{
  __shared__ __align__(16) int8_t sAh[128 * 64];
  __shared__ __align__(16) int8_t sAl[128 * 64];
  __shared__ __align__(16) int8_t sBh[64 * 64];
  __shared__ __align__(16) int8_t sBl[64 * 64];

  const int tid  = threadIdx.x;
  const int wave = tid >> 6;
  const int lane = tid & 63;
  const int quad = lane >> 4;
  const int t16  = lane & 15;
  const int wm   = wave & 1;   // row-half (2 x 64 rows)
  const int wn   = wave >> 1;  // col-half (2 x 32 cols)
  const int row0 = blockIdx.y * 128;
  const int col0 = blockIdx.x * 64;

  const int seg  = lane & 3;
  const int rsub = lane >> 2;

  int4v hh[4][2], cc[4][2], ll[4][2];
#pragma unroll
  for (int i = 0; i < 4; ++i)
#pragma unroll
    for (int j = 0; j < 2; ++j) {
      hh[i][j] = (int4v){0, 0, 0, 0};
      cc[i][j] = (int4v){0, 0, 0, 0};
      ll[i][j] = (int4v){0, 0, 0, 0};
    }

  for (int k0 = 0; k0 < 1024; k0 += 64) {
#pragma unroll
    for (int r = 0; r < 2; ++r) {
      const int trow = r * 64 + wave * 16;
      const size_t goffA = (size_t)(row0 + trow + rsub) * 1024 + k0 + seg * 16;
      GLOAD_LDS16(Ahi + goffA, &sAh[trow * 64]);
      GLOAD_LDS16(Alo + goffA, &sAl[trow * 64]);
    }
    {
      const int trow = wave * 16;  // 64 B rows, one pass
      const size_t goffB = (size_t)(col0 + trow + rsub) * 1024 + k0 + seg * 16;
      GLOAD_LDS16(Bhi + goffB, &sBh[trow * 64]);
      GLOAD_LDS16(Blo + goffB, &sBl[trow * 64]);
    }
    __syncthreads();

    int4v ah[4], al[4], bh[2], bl[2];
#pragma unroll
    for (int i = 0; i < 4; ++i) {
      const int ar = (wm * 64 + i * 16 + t16) * 64 + quad * 16;
      ah[i] = *(const int4v*)&sAh[ar];
      al[i] = *(const int4v*)&sAl[ar];
    }
#pragma unroll
    for (int j = 0; j < 2; ++j) {
      const int br = (wn * 32 + j * 16 + t16) * 64 + quad * 16;
      bh[j] = *(const int4v*)&sBh[br];
      bl[j] = *(const int4v*)&sBl[br];
    }

#pragma unroll
    for (int i = 0; i < 4; ++i)
#pragma unroll
      for (int j = 0; j < 2; ++j) {
        hh[i][j] = __builtin_amdgcn_mfma_i32_16x16x64_i8(ah[i], bh[j], hh[i][j], 0, 0, 0);
        cc[i][j] = __builtin_amdgcn_mfma_i32_16x16x64_i8(ah[i], bl[j], cc[i][j], 0, 0, 0);
        cc[i][j] = __builtin_amdgcn_mfma_i32_16x16x64_i8(al[i], bh[j], cc[i][j], 0, 0, 0);
        ll[i][j] = __builtin_amdgcn_mfma_i32_16x16x64_i8(al[i], bl[j], ll[i][j], 0, 0, 0);
      }
    __syncthreads();
  }

#pragma unroll
  for (int i = 0; i < 4; ++i) {
#pragma unroll
    for (int j = 0; j < 2; ++j) {
      const int ccol = col0 + wn * 32 + j * 16 + t16;
      const float* bp = (ccol < 1024) ? biasQ : (biasK - 1024);
#pragma unroll
      for (int r = 0; r < 4; ++r) {
        const int crow = row0 + wm * 64 + i * 16 + quad * 4 + r;
        float v = P_HH * (float)hh[i][j][r] + P_X * (float)cc[i][j][r] +
                  P_LL * (float)ll[i][j][r] + bp[ccol];
        int hi = (int)lrintf(v * INV_S256);
        hi = hi > 127 ? 127 : (hi < -127 ? -127 : hi);
        int lo = (int)lrintf(v * INV_S - 256.0f * (float)hi);
        lo = lo > 127 ? 127 : (lo < -127 ? -127 : lo);
        Ch[(size_t)crow * 2048 + ccol] = (int8_t)hi;
        Cl[(size_t)crow * 2048 + ccol] = (int8_t)lo;
      }
    }
  }
}

// ---------------------------------------------------------------------------
// AV: out_part = attn * x. fp16 MFMA, split-K=2, XCD-aware swizzle: linear
// grid 512; all 16 blocks (8 cols x 2 z) of one 128-row band share
// (linear id mod 8) -> same XCD -> attn band stays in that XCD's L2.
// A = attn fp16 rows of S (stride 8192 uint16), B = xT fp16 [1024 x 4096].
__global__ __launch_bounds__(256) void gemm_av(
    const uint16_t* __restrict__ A, const uint16_t* __restrict__ B,
    float* __restrict__ part)
{
  __shared__ uint16_t sA[128 * 32];
  __shared__ uint16_t sB[128 * 32];

  const int L    = blockIdx.x;          // 0..511
  const int slot = L >> 3;              // 0..63
  const int band = (L & 7) + 8 * (slot >> 4);   // 0..31  (same XCD per band)
  const int rem  = slot & 15;
  const int xcol = rem & 7;             // 0..7
  const int z    = rem >> 3;            // 0..1

  const int tid  = threadIdx.x;
  const int wave = tid >> 6;
  const int lane = tid & 63;
  const int quad = lane >> 4;
  const int t16  = lane & 15;
  const int wm   = wave & 1;
  const int wn   = wave >> 1;
  const int row0 = band * 128;
  const int col0 = xcol * 128;

  const int seg  = lane & 3;
  const int rsub = lane >> 2;

  float4v acc[4][4];
#pragma unroll
  for (int i = 0; i < 4; ++i)
#pragma unroll
    for (int j = 0; j < 4; ++j)
      acc[i][j] = (float4v){0.f, 0.f, 0.f, 0.f};

  const int k_begin = z * 2048, k_end = k_begin + 2048;
  for (int k0 = k_begin; k0 < k_end; k0 += 32) {
#pragma unroll
    for (int r = 0; r < 2; ++r) {
      const int trow = r * 64 + wave * 16;
      const size_t goffA = (size_t)(row0 + trow + rsub) * 8192 + k0 + seg * 8;
      const size_t goffB = (size_t)(col0 + trow + rsub) * 4096 + k0 + seg * 8;
      GLOAD_LDS16(A + goffA, &sA[trow * 32]);
      GLOAD_LDS16(B + goffB, &sB[trow * 32]);
    }
    __syncthreads();

    half8 af[4], bf[4];
#pragma unroll
    for (int i = 0; i < 4; ++i)
      af[i] = *(const half8*)&sA[(wm * 64 + i * 16 + t16) * 32 + quad * 8];
#pragma unroll
    for (int j = 0; j < 4; ++j)
      bf[j] = *(const half8*)&sB[(wn * 64 + j * 16 + t16) * 32 + quad * 8];

#pragma unroll
    for (int i = 0; i < 4; ++i)
#pragma unroll
      for (int j = 0; j < 4; ++j)
        acc[i][j] = __builtin_amdgcn_mfma_f32_16x16x32_f16(af[i], bf[j], acc[i][j], 0, 0, 0);
    __syncthreads();
  }

#pragma unroll
  for (int i = 0; i < 4; ++i) {
#pragma unroll
    for (int j = 0; j < 4; ++j) {
      const int ccol = col0 + wn * 64 + j * 16 + t16;
#pragma unroll
      for (int r = 0; r < 4; ++r) {
        const int crow = row0 + wm * 64 + i * 16 + quad * 4 + r;
        part[(size_t)z * 4096 * 1024 + (size_t)crow * 1024 + ccol] = acc[i][j][r];
      }
    }
  }
}

// fp32 -> two i8 planes on an int16 grid (v ~ s*(256*hi+lo)), 4 elems/thread
__global__ __launch_bounds__(256) void quant_i8(
    const float* __restrict__ in, int8_t* __restrict__ hi, int8_t* __restrict__ lo,
    int n4, float inv_s256, float inv_s)
{
  int i = blockIdx.x * blockDim.x + threadIdx.x;
  if (i < n4) {
    float4 v = ((const float4*)in)[i];
    float vv[4] = {v.x, v.y, v.z, v.w};
    int hp = 0, lp = 0;
#pragma unroll
    for (int c = 0; c < 4; ++c) {
      int h = (int)lrintf(vv[c] * inv_s256);
      h = h > 127 ? 127 : (h < -127 ? -127 : h);
      int l = (int)lrintf(vv[c] * inv_s - 256.0f * (float)h);
      l = l > 127 ? 127 : (l < -127 ? -127 : l);
      hp |= (h & 0xff) << (8 * c);
      lp |= (l & 0xff) << (8 * c);
    }
    ((int*)hi)[i] = hp;
    ((int*)lo)[i] = lp;
  }
}

// x [4096 x 1024] fp32 -> xT [1024 x 4096] fp16
__global__ __launch_bounds__(1024) void transpose_cast_f16(
    const float* __restrict__ x, uint16_t* __restrict__ xT)
{
  __shared__ float tile[32][33];
  const int tx = threadIdx.x, ty = threadIdx.y;
  const int col = blockIdx.x * 32 + tx;
  const int row = blockIdx.y * 32 + ty;
  tile[ty][tx] = x[(size_t)row * 1024 + col];
  __syncthreads();
  __half h = __float2half_rn(tile[tx][ty]);
  xT[(size_t)(blockIdx.x * 32 + ty) * 4096 + blockIdx.y * 32 + tx] = *(uint16_t*)&h;
}

// per-row softmax over S fp32 [4096 x 4096]; attn fp16 written IN-PLACE into
// the first half of each 16 KB S row.
__global__ __launch_bounds__(1024) void softmax_rows(float* __restrict__ S)
{
  const int row = blockIdx.x;
  const size_t base = (size_t)row * 4096;
  const int tid = threadIdx.x;
  const int wid = tid >> 6, lane = tid & 63;
  __shared__ float red[16];

  float4 v = ((const float4*)(S + base))[tid];
  float m = fmaxf(fmaxf(v.x, v.y), fmaxf(v.z, v.w));
#pragma unroll
  for (int off = 32; off; off >>= 1) m = fmaxf(m, __shfl_xor(m, off));
  if (lane == 0) red[wid] = m;
  __syncthreads();
  float mall = red[0];
#pragma unroll
  for (int i = 1; i < 16; ++i) mall = fmaxf(mall, red[i]);

  float4 e;
  e.x = __expf(v.x - mall);
  e.y = __expf(v.y - mall);
  e.z = __expf(v.z - mall);
  e.w = __expf(v.w - mall);
  float s = e.x + e.y + e.z + e.w;
#pragma unroll
  for (int off = 32; off; off >>= 1) s += __shfl_xor(s, off);
  __syncthreads();
  if (lane == 0) red[wid] = s;
  __syncthreads();
  float sall = 0.f;
#pragma unroll
  for (int i = 0; i < 16; ++i) sall += red[i];
  const float inv = 1.0f / sall;

  union { __half h[4]; short4 s4; } u;
  u.h[0] = __float2half_rn(e.x * inv);
  u.h[1] = __float2half_rn(e.y * inv);
  u.h[2] = __float2half_rn(e.z * inv);
  u.h[3] = __float2half_rn(e.w * inv);
  ((short4*)S)[(size_t)row * 2048 + tid] = u.s4;
}

// out = p0 + p1 (split-K reduce)
__global__ __launch_bounds__(256) void add2(
    const float* __restrict__ p0, const float* __restrict__ p1,
    float* __restrict__ out, int n4)
{
  int i = blockIdx.x * blockDim.x + threadIdx.x;
  if (i < n4) {
    float4 a = ((const float4*)p0)[i];
    float4 b = ((const float4*)p1)[i];
    float4 o = {a.x + b.x, a.y + b.y, a.z + b.z, a.w + b.w};
    ((float4*)out)[i] = o;
  }
}

extern "C" void kernel_launch(void* const* d_in, const int* in_sizes, int n_in,
                              void* d_out, int out_size, void* d_ws, size_t ws_size,
                              hipStream_t stream) {
  const int N = 4096, D = 1024;
  const float* x  = (const float*)d_in[0];
  const float* Wq = (const float*)d_in[1];
  const float* bq = (const float*)d_in[2];
  const float* Wk = (const float*)d_in[3];
  const float* bk = (const float*)d_in[4];
  float* out = (float*)d_out;

  // workspace layout (MiB offsets), total 108 MiB
  char* w = (char*)d_ws;
  const size_t MiB = 1024 * 1024;
  int8_t*   xq_hi  = (int8_t*)  (w + 0   * MiB);  // [N x D]      (dead after proj)
  int8_t*   xq_lo  = (int8_t*)  (w + 4   * MiB);  //              (dead after proj)
  int8_t*   Wqk_hi = (int8_t*)  (w + 8   * MiB);  // [2048 x D]   (dead after proj)
  int8_t*   Wqk_lo = (int8_t*)  (w + 10  * MiB);  //              (dead after proj)
  int8_t*   qk_hi  = (int8_t*)  (w + 12  * MiB);  // [N x 2048]   (dead after S)
  int8_t*   qk_lo  = (int8_t*)  (w + 20  * MiB);  //              (dead after S)
  float*    S      = (float*)   (w + 36  * MiB);  // [N x N] fp32, 64 MiB
  uint16_t* xTh    = (uint16_t*)(w + 100 * MiB);  // [D x N] fp16 (live until AV)
  float*    part0  = (float*)   (w + 0   * MiB);  // [N x D] fp32 (reuses xq/Wqk/qk)
  float*    part1  = (float*)   (w + 16  * MiB);  // [N x D] fp32 (reuses qk)

  // 1) quantize x, Wq, Wk to i8 planes; transpose-cast x to fp16
  quant_i8<<<N * D / 4 / 256, 256, 0, stream>>>(x, xq_hi, xq_lo, N * D / 4,
                                                INV_S256, INV_S);
  quant_i8<<<D * D / 4 / 256, 256, 0, stream>>>(Wq, Wqk_hi, Wqk_lo, D * D / 4,
                                                512.0f, 131072.0f);
  quant_i8<<<D * D / 4 / 256, 256, 0, stream>>>(Wk, Wqk_hi + (size_t)D * D,
                                                Wqk_lo + (size_t)D * D, D * D / 4,
                                                512.0f, 131072.0f);
  transpose_cast_f16<<<dim3(D / 32, N / 32), dim3(32, 32), 0, stream>>>(x, xTh);

  // 2) fused qk projection, i8 4-MFMA exact -> q/k i8 planes [N x 2048]
  gemm_proj_i8<<<dim3(2048 / 64, N / 128), 256, 0, stream>>>(
      xq_hi, xq_lo, Wqk_hi, Wqk_lo, bq, bk, qk_hi, qk_lo);

  // 3) S = q k^T via i8 split GEMM (q = cols 0..1023, k = cols 1024..2047)
  gemm_s_i8<<<dim3(N / 128, N / 128), 256, 0, stream>>>(
      qk_hi, qk_lo, qk_hi + 1024, qk_lo + 1024, S);

  // 4) softmax rows, attn fp16 in-place into S rows (stride 8192 uint16)
  softmax_rows<<<N, 1024, 0, stream>>>(S);

  // 5) out = attn * x, fp16, split-K=2, XCD-swizzled linear grid
  gemm_av<<<512, 256, 0, stream>>>((const uint16_t*)S, xTh, part0);

  // 6) reduce partials (gemm_av wrote z=1 at part0 + 16 MiB = part1)
  add2<<<N * D / 4 / 256, 256, 0, stream>>>(part0, part1, out, N * D / 4);

  (void)in_sizes; (void)n_in; (void)out_size; (void)ws_size;
}